// Round 14
// baseline (240.230 us; speedup 1.0000x reference)
//
#include <hip/hip_runtime.h>
#include <hip/hip_bf16.h>
#include <stdint.h>
#include <limits.h>

#define B_   2
#define N_   20000
#define S_   1024
#define C_   256
#define NS_  16
#define NQ   (B_ * S_)        // 2048 queries
#define M_   (NQ * NS_)       // 32768 MLP rows
#define K1P  288              // 259 padded to multiple of 32
#define O1   512
#define O2   256
#define O3   256
#define OUTC 96

#define R2C   ((float)(0.05 * 0.05))
#define HMINC ((float)(-0.02))
#define HMAXC ((float)(0.04))

// spatial grid for cyl query
#define GDIM   16
#define GCELLS (GDIM * GDIM * GDIM)          // 4096 per batch
#define GTOT   (B_ * GCELLS)                 // 8192
#define CAP    256                           // per-wave candidate buffer
#define TBLK   10000                         // transpose blocks fused into query dispatch

__device__ __forceinline__ unsigned short f2b(float f) {
    union { float f; unsigned int i; } x; x.f = f;
    unsigned int r = x.i + 0x7FFFu + ((x.i >> 16) & 1u);   // RNE
    return (unsigned short)(r >> 16);
}

// async global->LDS 16B copy (LDS dest = wave-uniform base + lane*16)
__device__ __forceinline__ void gl16(const unsigned short* g, unsigned short* l) {
    __builtin_amdgcn_global_load_lds(
        (const __attribute__((address_space(1))) unsigned int*)g,
        (__attribute__((address_space(3))) unsigned int*)l,
        16, 0, 0);
}

// ---------------------------------------------------------------- weight prep (fp32 -> bf16) + grid zero
__global__ __launch_bounds__(256) void prep_w123z(const float* __restrict__ m1w,
                                                  const float* __restrict__ m2w,
                                                  const float* __restrict__ m3w,
                                                  unsigned short* __restrict__ w1p,
                                                  unsigned short* __restrict__ w2p,
                                                  unsigned short* __restrict__ w3p,
                                                  int* __restrict__ gcnt) {
    int i = blockIdx.x * 256 + threadIdx.x;
    if (i < GTOT) gcnt[i] = 0;
    if (i < O1 * K1P) {
        int o = i / K1P, k = i - o * K1P;
        float v = 0.0f;
        if (k < 256)      v = m1w[o * 259 + 3 + k];
        else if (k < 259) v = m1w[o * 259 + (k - 256)];
        w1p[i] = (k < 259) ? f2b(v) : (unsigned short)0;
    } else if (i < O1 * K1P + O2 * 512) {
        int j = i - O1 * K1P;
        w2p[j] = f2b(m2w[j]);
    } else if (i < O1 * K1P + O2 * 512 + O3 * 256) {
        int j = i - O1 * K1P - O2 * 512;
        w3p[j] = f2b(m3w[j]);
    }
}

// ---------------------------------------------------------------- grid build: count / scan / scatter
__device__ __forceinline__ int cell_of(float px, float py, float pz, int b) {
    int cx = (int)(px * (float)GDIM); cx = min(GDIM - 1, max(0, cx));
    int cy = (int)(py * (float)GDIM); cy = min(GDIM - 1, max(0, cy));
    int cz = (int)(pz * (float)GDIM); cz = min(GDIM - 1, max(0, cz));
    return b * GCELLS + cz * (GDIM * GDIM) + cy * GDIM + cx;
}

__global__ __launch_bounds__(256) void grid_count(const float* __restrict__ xyz,
                                                  int* __restrict__ counts) {
    int i = blockIdx.x * 256 + threadIdx.x;
    if (i < B_ * N_) {
        int b = i / N_;
        const float* p = xyz + (size_t)i * 3;
        atomicAdd(counts + cell_of(p[0], p[1], p[2], b), 1);
    }
}

// one block, wave-parallel hierarchical scan
__global__ __launch_bounds__(256) void grid_scan(const int* __restrict__ counts,
                                                 int* __restrict__ start,
                                                 int* __restrict__ cursor) {
    __shared__ int wsum[4];
    int t = threadIdx.x, lane = t & 63, wv = t >> 6;
    int local[32];
    int s = 0;
#pragma unroll
    for (int i = 0; i < 32; ++i) { local[i] = counts[t * 32 + i]; s += local[i]; }
    int incl = s;
#pragma unroll
    for (int off = 1; off < 64; off <<= 1) {
        int u = __shfl_up(incl, off);
        if (lane >= off) incl += u;
    }
    if (lane == 63) wsum[wv] = incl;
    __syncthreads();
    int add = 0;
    for (int i = 0; i < wv; ++i) add += wsum[i];
    int r = incl - s + add;                   // exclusive prefix of this thread's 32-chunk
#pragma unroll
    for (int i = 0; i < 32; ++i) {
        start[t * 32 + i] = r;
        cursor[t * 32 + i] = r;
        r += local[i];
    }
    if (t == 255) start[GTOT] = r;
}

__global__ __launch_bounds__(256) void grid_scatter(const float* __restrict__ xyz,
                                                    int* __restrict__ cursor,
                                                    float4* __restrict__ sorted) {
    int i = blockIdx.x * 256 + threadIdx.x;
    if (i < B_ * N_) {
        int b = i / N_, n = i - b * N_;
        const float* p = xyz + (size_t)i * 3;
        float px = p[0], py = p[1], pz = p[2];
        int pos = atomicAdd(cursor + cell_of(px, py, pz, b), 1);
        sorted[pos] = make_float4(px, py, pz, __int_as_float(n));
    }
}

// ---------------------------------------------------------------- wave-parallel select-16-smallest
__device__ __forceinline__ void sort16(int* buf, int cnt, int lane) {
    asm volatile("s_waitcnt lgkmcnt(0)" ::: "memory");
    __builtin_amdgcn_sched_barrier(0);
    int a0 = INT_MAX, a1 = INT_MAX, a2 = INT_MAX, a3 = INT_MAX;
    if (lane < cnt)       a0 = buf[lane];
    if (lane + 64 < cnt)  a1 = buf[lane + 64];
    if (lane + 128 < cnt) a2 = buf[lane + 128];
    if (lane + 192 < cnt) a3 = buf[lane + 192];
#pragma unroll
    for (int t = 0; t < NS_; ++t) {
        int v = a0, sl = 0;
        if (a1 < v) { v = a1; sl = 1; }
        if (a2 < v) { v = a2; sl = 2; }
        if (a3 < v) { v = a3; sl = 3; }
        int pp = (sl << 6) | lane;
#pragma unroll
        for (int off = 1; off < 64; off <<= 1) {
            int ov = __shfl_xor(v, off);
            int op = __shfl_xor(pp, off);
            if (ov < v) { v = ov; pp = op; }
        }
        if ((pp & 63) == lane) {
            int s = pp >> 6;
            if (s == 0) a0 = INT_MAX;
            else if (s == 1) a1 = INT_MAX;
            else if (s == 2) a2 = INT_MAX;
            else a3 = INT_MAX;
        }
        if (lane == 0) buf[t] = v;
    }
    asm volatile("s_waitcnt lgkmcnt(0)" ::: "memory");
    __builtin_amdgcn_sched_barrier(0);
}

// ---------------------------------------------------------------- fused cylinder query + feature transpose
// blockIdx < NQ: one block (4 waves) per query (cell filter + compacted scan).
// blockIdx >= NQ: 32x32 transpose tile of feat [B][C][N] fp32 -> feat_t [B][N][C] bf16.
// Independent outputs; transpose blocks backfill CUs behind query stragglers.
__global__ __launch_bounds__(256) void query_transpose(const float* __restrict__ new_xyz,
                                                       const float* __restrict__ view_rot,
                                                       const float4* __restrict__ sorted,
                                                       const int* __restrict__ cell_start,
                                                       const float* __restrict__ feat,
                                                       int* __restrict__ idx_out,
                                                       unsigned short* __restrict__ feat_t) {
#pragma clang fp contract(off)
    __shared__ int bufs[4][CAP];
    __shared__ int tots[4];
    __shared__ int spnE[4][64];      // exclusive prefix of span lengths (monotone)
    __shared__ int spnS[4][64];      // span starts
    __shared__ float tile[32][33];   // transpose role

    if (blockIdx.x >= NQ) {          // ---------------- transpose role
        int t5 = blockIdx.x - NQ;                 // 0..9999
        int n0 = (t5 % 625) * 32;
        int rem = t5 / 625;                       // 0..15
        int c0 = (rem & 7) * 32;
        int b = rem >> 3;
        int t = threadIdx.x;
        int nl = t & 31;
#pragma unroll
        for (int i = 0; i < 4; ++i) {
            int cl = (t >> 5) + i * 8;
            tile[cl][nl] = feat[((size_t)(b * C_ + c0 + cl)) * N_ + n0 + nl];
        }
        __syncthreads();
        int nr = t >> 3, c4 = (t & 7) * 4;
        ushort4 v;
        v.x = f2b(tile[c4 + 0][nr]);
        v.y = f2b(tile[c4 + 1][nr]);
        v.z = f2b(tile[c4 + 2][nr]);
        v.w = f2b(tile[c4 + 3][nr]);
        *(ushort4*)(feat_t + ((size_t)(b * N_ + n0 + nr)) * C_ + c0 + c4) = v;
        return;
    }

    // ---------------- query role
    int w = threadIdx.x >> 6, lane = threadIdx.x & 63;
    int q = blockIdx.x;
    int b = q >> 10;                 // S_ = 1024
    int* buf = bufs[w];

    const float* nq = new_xyz + (size_t)q * 3;
    float qx = nq[0], qy = nq[1], qz = nq[2];
    const float* rp = view_rot + (size_t)q * 9;
    float R[9];
#pragma unroll
    for (int i = 0; i < 9; ++i) R[i] = rp[i];
    float dq0 = (R[0]*qx + R[1]*qy) + R[2]*qz;
    float dq1 = (R[3]*qx + R[4]*qy) + R[5]*qz;
    float dq2 = (R[6]*qx + R[7]*qy) + R[8]*qz;

    // ---- AABB of {p : hmin < r0 < hmax, r1^2+r2^2 < R^2}, r = V(p-q), via M = V^-1
    int x0 = 0, x1 = GDIM - 1, y0 = 0, y1 = GDIM - 1, z0 = 0, z1 = GDIM - 1;
    {
        float det = R[0]*(R[4]*R[8]-R[5]*R[7])
                  - R[1]*(R[3]*R[8]-R[5]*R[6])
                  + R[2]*(R[3]*R[7]-R[4]*R[6]);
        float adet = fabsf(det);
        if (adet > 1e-30f) {
            float id = 1.0f / det;
            float m00 = (R[4]*R[8]-R[5]*R[7])*id, m01 = (R[2]*R[7]-R[1]*R[8])*id, m02 = (R[1]*R[5]-R[2]*R[4])*id;
            float m10 = (R[5]*R[6]-R[3]*R[8])*id, m11 = (R[0]*R[8]-R[2]*R[6])*id, m12 = (R[2]*R[3]-R[0]*R[5])*id;
            float m20 = (R[3]*R[7]-R[4]*R[6])*id, m21 = (R[1]*R[6]-R[0]*R[7])*id, m22 = (R[0]*R[4]-R[1]*R[3])*id;
            const float mid = 0.5f * (HMINC + HMAXC);   // 0.01
            const float hh  = 0.5f * (HMAXC - HMINC);   // 0.03
            float cx = qx + m00 * mid, cy = qy + m10 * mid, cz = qz + m20 * mid;
            float ex = hh * fabsf(m00) + 0.05f * sqrtf(m01*m01 + m02*m02);
            float ey = hh * fabsf(m10) + 0.05f * sqrtf(m11*m11 + m12*m12);
            float ez = hh * fabsf(m20) + 0.05f * sqrtf(m21*m21 + m22*m22);
            ex = ex * 1.002f + 1e-3f;                   // conservative fp margin
            ey = ey * 1.002f + 1e-3f;
            ez = ez * 1.002f + 1e-3f;
            x0 = (int)fmaxf(0.0f, fminf((float)(GDIM - 1), floorf((cx - ex) * (float)GDIM)));
            x1 = (int)fmaxf(0.0f, fminf((float)(GDIM - 1), floorf((cx + ex) * (float)GDIM)));
            y0 = (int)fmaxf(0.0f, fminf((float)(GDIM - 1), floorf((cy - ey) * (float)GDIM)));
            y1 = (int)fmaxf(0.0f, fminf((float)(GDIM - 1), floorf((cy + ey) * (float)GDIM)));
            z0 = (int)fmaxf(0.0f, fminf((float)(GDIM - 1), floorf((cz - ez) * (float)GDIM)));
            z1 = (int)fmaxf(0.0f, fminf((float)(GDIM - 1), floorf((cz + ez) * (float)GDIM)));
        }
    }

    int ny = y1 - y0 + 1, nz = z1 - z0 + 1;
    int cnt = 0, tot = 0;
    int cbase = b * GCELLS;

    {
        int NR = ny * nz;                         // rows (z,y) in AABB, <= 256
        int nr_w = (NR - w + 3) >> 2;             // rows for this wave (stride 4)
        const float inv16 = 0.0625f, half = 0.03125f;
        float ax = (fabsf(R[0]) + fabsf(R[1]) + fabsf(R[2])) * half + 2e-4f;
        float ay = (fabsf(R[3]) + fabsf(R[4]) + fabsf(R[5])) * half + 2e-4f;
        float az = (fabsf(R[6]) + fabsf(R[7]) + fabsf(R[8])) * half + 2e-4f;
        int sl = 0, el = 0;
        if (lane < nr_w) {                        // one row per lane: tighten x-range
            int ri = w + (lane << 2);
            int zi = ri / ny;
            int yi = ri - zi * ny;
            float cy0 = (y0 + yi + 0.5f) * inv16;
            float cz0 = (z0 + zi + 0.5f) * inv16;
            float cx0 = (x0 + 0.5f) * inv16;
            float xr = (R[0]*cx0 + R[1]*cy0) + R[2]*cz0 - dq0;
            float yr = (R[3]*cx0 + R[4]*cy0) + R[5]*cz0 - dq1;
            float zr = (R[6]*cx0 + R[7]*cy0) + R[8]*cz0 - dq2;
            float sx = R[0] * inv16, sy = R[3] * inv16, sz = R[6] * inv16;
            int xa = 1 << 28, xb = -1;
            for (int cx = x0; cx <= x1; ++cx) {
                bool px = (xr + ax > HMINC) && (xr - ax < HMAXC);
                float dy = fmaxf(fabsf(yr) - ay, 0.0f);
                float dz = fmaxf(fabsf(zr) - az, 0.0f);
                bool pr = (dy*dy + dz*dz) < (R2C + 1e-5f);
                if (px && pr) { if (cx < xa) xa = cx; xb = cx; }
                xr += sx; yr += sy; zr += sz;
            }
            if (xb >= xa) {
                int cid = cbase + (z0 + zi) * (GDIM * GDIM) + (y0 + yi) * GDIM;
                sl = cell_start[cid + xa];
                el = cell_start[cid + xb + 1];
            }
        }

        // ---- work compaction: prefix-sum span lengths across the wave
        int len = el - sl;                        // 0 for inactive/pruned lanes
        int incl = len;
#pragma unroll
        for (int off = 1; off < 64; off <<= 1) {
            int v = __shfl_up(incl, off);
            if (lane >= off) incl += v;
        }
        int T = __shfl(incl, 63);
        spnE[w][lane] = incl - len;
        spnS[w][lane] = sl;
        asm volatile("s_waitcnt lgkmcnt(0)" ::: "memory");
        __builtin_amdgcn_sched_barrier(0);

        for (int g0 = 0; g0 < T; g0 += 64) {
            int g = g0 + lane;
            bool m = false; int n = 0;
            if (g < T) {
                int lo = 0, hi = 63;              // largest j with spnE[j] <= g
#pragma unroll
                for (int it = 0; it < 6; ++it) {
                    int mid = (lo + hi + 1) >> 1;
                    if (spnE[w][mid] <= g) lo = mid; else hi = mid - 1;
                }
                int p = spnS[w][lo] + (g - spnE[w][lo]);
                float4 v = sorted[p];
                n = __float_as_int(v.w);
                float px = v.x, py = v.y, pz = v.z;
                float xr = ((R[0]*px + R[1]*py) + R[2]*pz) - dq0;
                float yr = ((R[3]*px + R[4]*py) + R[5]*pz) - dq1;
                float zr = ((R[6]*px + R[7]*py) + R[8]*pz) - dq2;
                m = ((yr*yr + zr*zr) < R2C) && (xr > HMINC) && (xr < HMAXC);
            }
            unsigned long long bal = __ballot(m);
            if (m) {
                int pos = cnt + __popcll(bal & ((1ull << lane) - 1ull));
                buf[pos] = n;
            }
            int h = __popcll(bal);
            cnt += h; tot += h;
            if (cnt > CAP - 64) { sort16(buf, cnt, lane); cnt = NS_; }
        }
    }

    // per-wave finalize: best 16 ascending in bufs[w][0..15], INT_MAX padded
    sort16(buf, cnt, lane);
    if (lane == 0) tots[w] = tot;
    __syncthreads();

    // merge 4x16 candidates -> global best 16 (wave 0 only)
    if (w == 0) {
        int cand = bufs[lane >> 4][lane & 15];
        int myv = INT_MAX;
#pragma unroll
        for (int t = 0; t < NS_; ++t) {
            int v = cand, pp = lane;
#pragma unroll
            for (int off = 1; off < 64; off <<= 1) {
                int ov = __shfl_xor(v, off);
                int op = __shfl_xor(pp, off);
                if (ov < v) { v = ov; pp = op; }
            }
            if (lane == t) myv = v;               // lane t keeps t-th smallest
            if (pp == lane) cand = INT_MAX;       // owner retires
        }
        int tt = tots[0] + tots[1] + tots[2] + tots[3];
        int total = tt < NS_ ? tt : NS_;
        int first = (tt > 0) ? __shfl(myv, 0) : 0;
        if (lane < NS_)
            idx_out[q * NS_ + lane] = (lane < total) ? myv : first;
    }
}

// ---------------------------------------------------------------- gather + h0
__global__ __launch_bounds__(256) void build_h0(const float* __restrict__ xyz,
                                                const float* __restrict__ new_xyz,
                                                const float* __restrict__ view_rot,
                                                const unsigned short* __restrict__ feat_t,
                                                const int* __restrict__ idxs,
                                                unsigned short* __restrict__ h0) {
#pragma clang fp contract(off)
    int q = blockIdx.x;
    int b = q >> 10;
    int t = threadIdx.x;
    __shared__ int pidx[NS_];
    if (t < NS_) pidx[t] = idxs[q * NS_ + t];
    __syncthreads();

#pragma unroll
    for (int pass = 0; pass < 2; ++pass) {
        int n = pass * 8 + (t >> 5);
        int p = pidx[n];
        uint4 v = *(const uint4*)(feat_t + ((size_t)(b * N_ + p)) * C_ + (t & 31) * 8);
        *(uint4*)(h0 + (size_t)(q * NS_ + n) * K1P + (t & 31) * 8) = v;
    }

    if (t < NS_) {
        int n = t, p = pidx[n];
        const float* pp = xyz + ((size_t)b * N_ + p) * 3;
        const float* nq = new_xyz + (size_t)q * 3;
        float dx = (pp[0] - nq[0]) / 0.05f;
        float dy = (pp[1] - nq[1]) / 0.05f;
        float dz = (pp[2] - nq[2]) / 0.05f;
        const float* rp = view_rot + (size_t)q * 9;
        float r0 = (dx * rp[0] + dy * rp[3]) + dz * rp[6];
        float r1 = (dx * rp[1] + dy * rp[4]) + dz * rp[7];
        float r2 = (dx * rp[2] + dy * rp[5]) + dz * rp[8];
        size_t row = (size_t)(q * NS_ + n) * K1P;
        h0[row + 256] = f2b(r0);
        h0[row + 257] = f2b(r1);
        h0[row + 258] = f2b(r2);
    }
    for (int e = t; e < NS_ * 29; e += 256) {          // zero pad cols 259..287
        int n = e / 29, c = 259 + (e - n * 29);
        h0[(size_t)(q * NS_ + n) * K1P + c] = 0;
    }
}

// ---------------------------------------------------------------- MFMA GEMM + BN + ReLU (gemm1 only)
typedef float f32x4 __attribute__((ext_vector_type(4)));
typedef short s16x8 __attribute__((ext_vector_type(8)));

__global__ __launch_bounds__(256) void gemm_bn_relu(const unsigned short* __restrict__ A,
                                                    const unsigned short* __restrict__ W,
                                                    const float* __restrict__ bias,
                                                    const float* __restrict__ gam,
                                                    const float* __restrict__ bet,
                                                    unsigned short* __restrict__ out,
                                                    int M, int Nn, int K) {
    __shared__ __align__(16) unsigned short As[128 * 32];
    __shared__ __align__(16) unsigned short Bs[128 * 32];
    int tid  = threadIdx.x;
    int lane = tid & 63, wave = tid >> 6;
    int m0 = blockIdx.x * 128, n0 = blockIdx.y * 128;
    int wm = (wave >> 1) * 64, wn = (wave & 1) * 64;

    f32x4 acc[4][4] = {};

    for (int k0 = 0; k0 < K; k0 += 32) {
        __syncthreads();
#pragma unroll
        for (int j = 0; j < 2; ++j) {
            int e = j * 256 + tid;
            int r = e >> 2, c8 = (e & 3) << 3;
            gl16(A + (size_t)(m0 + r) * K + k0 + c8, &As[e * 8]);
            gl16(W + (size_t)(n0 + r) * K + k0 + c8, &Bs[e * 8]);
        }
        __syncthreads();

        int kq = (lane >> 4) * 8, rr = lane & 15;
        s16x8 af[4], bfr[4];
#pragma unroll
        for (int i = 0; i < 4; ++i) af[i]  = *(const s16x8*)&As[(wm + i * 16 + rr) * 32 + kq];
#pragma unroll
        for (int j = 0; j < 4; ++j) bfr[j] = *(const s16x8*)&Bs[(wn + j * 16 + rr) * 32 + kq];
#pragma unroll
        for (int i = 0; i < 4; ++i)
#pragma unroll
            for (int j = 0; j < 4; ++j)
                acc[i][j] = __builtin_amdgcn_mfma_f32_16x16x32_bf16(af[i], bfr[j], acc[i][j], 0, 0, 0);
    }

    float inv = 1.0f / sqrtf(1.0f + 1e-5f);
    int col = lane & 15, rq = (lane >> 4) * 4;
#pragma unroll
    for (int j = 0; j < 4; ++j) {
        int n = n0 + wn + j * 16 + col;
        float sc = gam[n] * inv;
        float tb = bias[n] * sc + bet[n];
#pragma unroll
        for (int i = 0; i < 4; ++i) {
            int mbase = m0 + wm + i * 16 + rq;
#pragma unroll
            for (int r = 0; r < 4; ++r) {
                float v = acc[i][j][r] * sc + tb;
                v = fmaxf(v, 0.0f);
                out[(size_t)(mbase + r) * Nn + n] = f2b(v);
            }
        }
    }
}

// ---------------------------------------------------------------- fused gemm2 + gemm3 + maxpool (+ head-weight prep)
// 64-row blocks (4 queries), 512 threads (8 waves: 4 m-strips x 2 n-halves), LDS 52 KB
// -> 2-3 blocks/CU co-resident, phases overlap across blocks.
__global__ __launch_bounds__(512) void gemm23_pool(const unsigned short* __restrict__ A,   // h1 [M][512]
                                                   const unsigned short* __restrict__ W2,  // [256][512]
                                                   const float* __restrict__ bias2,
                                                   const float* __restrict__ gam2,
                                                   const float* __restrict__ bet2,
                                                   const unsigned short* __restrict__ W3,  // [256][256]
                                                   const float* __restrict__ bias3,
                                                   const float* __restrict__ gam3,
                                                   const float* __restrict__ bet3,
                                                   const float* __restrict__ c1w,
                                                   const float* __restrict__ c2w,
                                                   const float* __restrict__ c3w,
                                                   unsigned short* __restrict__ wprep,
                                                   unsigned short* __restrict__ hp) {      // [2048][256]
    __shared__ __align__(16) unsigned short As[64 * 32];     // 4 KB
    __shared__ __align__(16) unsigned short Bs[256 * 32];    // 16 KB
    __shared__ __align__(16) unsigned short H2[64 * 256];    // 32 KB, swizzled
    int tid = threadIdx.x, lane = tid & 63, wave = tid >> 6;
    int m0 = blockIdx.x * 64;
    int wm = (wave >> 1) * 16, wn = (wave & 1) * 128;
    int kq = (lane >> 4) * 8, rr = lane & 15;
    int col = lane & 15, rq = (lane >> 4) * 4;
    float inv = 1.0f / sqrtf(1.0f + 1e-5f);

    f32x4 acc[8] = {};

    // -------- phase 1: K=512
    for (int k0 = 0; k0 < 512; k0 += 32) {
        __syncthreads();
        if (tid < 256) {
            int r = tid >> 2, c8 = (tid & 3) << 3;
            gl16(A + (size_t)(m0 + r) * 512 + k0 + c8, &As[tid * 8]);
        }
#pragma unroll
        for (int j = 0; j < 2; ++j) {
            int e = j * 512 + tid;
            int r = e >> 2, c8 = (e & 3) << 3;
            gl16(W2 + (size_t)r * 512 + k0 + c8, &Bs[e * 8]);
        }
        __syncthreads();
        s16x8 af = *(const s16x8*)&As[(wm + rr) * 32 + kq];
        s16x8 bf[8];
#pragma unroll
        for (int j = 0; j < 8; ++j) bf[j] = *(const s16x8*)&Bs[(wn + j * 16 + rr) * 32 + kq];
#pragma unroll
        for (int j = 0; j < 8; ++j)
            acc[j] = __builtin_amdgcn_mfma_f32_16x16x32_bf16(af, bf[j], acc[j], 0, 0, 0);
    }

    // head-weight prep: 384 elements per block, disjoint (writes to dead-h0 region)
    {
        int e = blockIdx.x * 384 + tid;
        if (tid < 384) {
            int l = e >> 16, j = e & 65535, row = j >> 8, kcol = j & 255;
            float v;
            if (l == 0)      v = c1w[j];
            else if (l == 1) v = c2w[j];
            else             v = (row < OUTC) ? c3w[row * 256 + kcol] : 0.0f;
            int c = kcol & 127;
            wprep[l * 65536 + (kcol >> 7) * 32768 + row * 128 + (c ^ ((row & 7) << 3))] = f2b(v);
        }
    }

    // epilogue1: bn2+relu -> H2 (swizzled: byte ^= (row&7)<<4)
#pragma unroll
    for (int j = 0; j < 8; ++j) {
        int n = wn + j * 16 + col;
        float sc = gam2[n] * inv;
        float tb = bias2[n] * sc + bet2[n];
#pragma unroll
        for (int r = 0; r < 4; ++r) {
            int row = wm + rq + r;
            float v = fmaxf(acc[j][r] * sc + tb, 0.0f);
            *(unsigned short*)((char*)H2 + row * 512 + ((2 * n) ^ ((row & 7) << 4))) = f2b(v);
        }
    }

    // -------- phase 2: K=256 from H2(LDS), W3 streamed
#pragma unroll
    for (int j = 0; j < 8; ++j) acc[j] = (f32x4){0.f, 0.f, 0.f, 0.f};

    for (int k0 = 0; k0 < 256; k0 += 32) {
        __syncthreads();
#pragma unroll
        for (int j = 0; j < 2; ++j) {
            int e = j * 512 + tid;
            int r = e >> 2, c8 = (e & 3) << 3;
            gl16(W3 + (size_t)r * 256 + k0 + c8, &Bs[e * 8]);
        }
        __syncthreads();
        int row = wm + rr;
        s16x8 af = *(const s16x8*)((const char*)H2 + row * 512 + ((2 * (k0 + kq)) ^ ((row & 7) << 4)));
        s16x8 bf[8];
#pragma unroll
        for (int j = 0; j < 8; ++j) bf[j] = *(const s16x8*)&Bs[(wn + j * 16 + rr) * 32 + kq];
#pragma unroll
        for (int j = 0; j < 8; ++j)
            acc[j] = __builtin_amdgcn_mfma_f32_16x16x32_bf16(af, bf[j], acc[j], 0, 0, 0);
    }

    // epilogue2: bn3+relu + 16-row maxpool (each wave's 16 rows = 1 query)
    int qbase = (m0 + wm) >> 4;
#pragma unroll
    for (int j = 0; j < 8; ++j) {
        int n = wn + j * 16 + col;
        float sc = gam3[n] * inv;
        float tb = bias3[n] * sc + bet3[n];
        float mx = 0.0f;                          // relu floor
#pragma unroll
        for (int r = 0; r < 4; ++r)
            mx = fmaxf(mx, acc[j][r] * sc + tb);
        mx = fmaxf(mx, __shfl_xor(mx, 16, 64));
        mx = fmaxf(mx, __shfl_xor(mx, 32, 64));
        if (lane < 16)
            hp[(size_t)qbase * 256 + n] = f2b(mx);
    }
}

// ---------------------------------------------------------------- fused head: hp -> c1 -> c2 -> c3 -> out
__device__ __forceinline__ void head_gemm(const unsigned short* __restrict__ act,
                                          unsigned short* __restrict__ Ws,
                                          const unsigned short* __restrict__ Wp,  // layer base in wprep
                                          int tid, int lane, int wn, f32x4 acc[4][4]) {
    int kq = (lane >> 4) * 8, rr = lane & 15;
    for (int h = 0; h < 2; ++h) {
        __syncthreads();                          // Ws free (previous mma done)
        const unsigned short* src = Wp + h * 32768;
#pragma unroll
        for (int p = 0; p < 16; ++p)
            gl16(src + (p * 256 + tid) * 8, Ws + (p * 256 + tid) * 8);
        __syncthreads();                          // drains vmcnt -> Ws ready
        int k0 = h * 128;
#pragma unroll
        for (int kk = 0; kk < 128; kk += 32) {
            s16x8 af[4], bf[4];
#pragma unroll
            for (int i = 0; i < 4; ++i) {
                int row = i * 16 + rr;
                af[i] = *(const s16x8*)((const char*)act + row * 512 + ((2 * (k0 + kk + kq)) ^ ((row & 7) << 4)));
            }
#pragma unroll
            for (int j = 0; j < 4; ++j) {
                int row = wn + j * 16 + rr;
                bf[j] = *(const s16x8*)&Ws[row * 128 + ((kk + kq) ^ ((row & 7) << 3))];
            }
#pragma unroll
            for (int i = 0; i < 4; ++i)
#pragma unroll
                for (int j = 0; j < 4; ++j)
                    acc[i][j] = __builtin_amdgcn_mfma_f32_16x16x32_bf16(af[i], bf[j], acc[i][j], 0, 0, 0);
        }
    }
}

__global__ __launch_bounds__(256) void head_fused(const unsigned short* __restrict__ hp,
                                                  const unsigned short* __restrict__ wp,
                                                  const float* __restrict__ c1b,
                                                  const float* __restrict__ c1g, const float* __restrict__ c1be,
                                                  const float* __restrict__ c2b,
                                                  const float* __restrict__ c2g, const float* __restrict__ c2be,
                                                  const float* __restrict__ c3b,
                                                  float* __restrict__ out) {
    __shared__ __align__(16) unsigned short actA[64 * 256];   // 32 KB, swizzled
    __shared__ __align__(16) unsigned short actB[64 * 256];   // 32 KB, swizzled
    __shared__ __align__(16) unsigned short Ws[256 * 128];    // 64 KB, pre-swizzled halves
    int tid = threadIdx.x, lane = tid & 63, wave = tid >> 6;
    int q0 = blockIdx.x * 64;
    int wn = wave * 64, col = lane & 15, rq = (lane >> 4) * 4;
    float inv = 1.0f / sqrtf(1.0f + 1e-5f);

    // stage hp rows -> actA (swizzled)
#pragma unroll
    for (int j = 0; j < 8; ++j) {
        int c = j * 256 + tid;
        int row = c >> 5, cb = c & 31;
        uint4 v = *(const uint4*)(hp + (size_t)(q0 + row) * 256 + cb * 8);
        *(uint4*)((char*)actA + row * 512 + (((unsigned)cb << 4) ^ ((row & 7) << 4))) = v;
    }

    f32x4 acc[4][4];

    // ---- layer c1: actA -> actB
#pragma unroll
    for (int i = 0; i < 4; ++i)
#pragma unroll
        for (int j = 0; j < 4; ++j) acc[i][j] = (f32x4){0.f, 0.f, 0.f, 0.f};
    head_gemm(actA, Ws, wp, tid, lane, wn, acc);
#pragma unroll
    for (int j = 0; j < 4; ++j) {
        int n = wn + j * 16 + col;
        float sc = c1g[n] * inv, tb = c1b[n] * sc + c1be[n];
#pragma unroll
        for (int i = 0; i < 4; ++i)
#pragma unroll
            for (int r = 0; r < 4; ++r) {
                int row = i * 16 + rq + r;
                float v = fmaxf(acc[i][j][r] * sc + tb, 0.0f);
                *(unsigned short*)((char*)actB + row * 512 + ((2 * n) ^ ((row & 7) << 4))) = f2b(v);
            }
    }

    // ---- layer c2: actB -> actA
#pragma unroll
    for (int i = 0; i < 4; ++i)
#pragma unroll
        for (int j = 0; j < 4; ++j) acc[i][j] = (f32x4){0.f, 0.f, 0.f, 0.f};
    head_gemm(actB, Ws, wp + 65536, tid, lane, wn, acc);
#pragma unroll
    for (int j = 0; j < 4; ++j) {
        int n = wn + j * 16 + col;
        float sc = c2g[n] * inv, tb = c2b[n] * sc + c2be[n];
#pragma unroll
        for (int i = 0; i < 4; ++i)
#pragma unroll
            for (int r = 0; r < 4; ++r) {
                int row = i * 16 + rq + r;
                float v = fmaxf(acc[i][j][r] * sc + tb, 0.0f);
                *(unsigned short*)((char*)actA + row * 512 + ((2 * n) ^ ((row & 7) << 4))) = f2b(v);
            }
    }

    // ---- layer c3: actA -> out (fp32, N=96, no bn/relu)
#pragma unroll
    for (int i = 0; i < 4; ++i)
#pragma unroll
        for (int j = 0; j < 4; ++j) acc[i][j] = (f32x4){0.f, 0.f, 0.f, 0.f};
    head_gemm(actA, Ws, wp + 131072, tid, lane, wn, acc);
#pragma unroll
    for (int j = 0; j < 4; ++j) {
        int n = wn + j * 16 + col;
        if (n < OUTC) {
            float bb = c3b[n];
#pragma unroll
            for (int i = 0; i < 4; ++i)
#pragma unroll
                for (int r = 0; r < 4; ++r)
                    out[(size_t)(q0 + i * 16 + rq + r) * OUTC + n] = acc[i][j][r] + bb;
        }
    }
}

// ---------------------------------------------------------------- launch
extern "C" void kernel_launch(void* const* d_in, const int* in_sizes, int n_in,
                              void* d_out, int out_size, void* d_ws, size_t ws_size,
                              hipStream_t stream) {
    const float* xyz      = (const float*)d_in[0];
    const float* new_xyz  = (const float*)d_in[1];
    const float* view_rot = (const float*)d_in[2];
    const float* feat     = (const float*)d_in[3];
    const float* m1w = (const float*)d_in[4];
    const float* m1b = (const float*)d_in[5];
    const float* m1g = (const float*)d_in[6];
    const float* m1be= (const float*)d_in[7];
    const float* m2w = (const float*)d_in[8];
    const float* m2b = (const float*)d_in[9];
    const float* m2g = (const float*)d_in[10];
    const float* m2be= (const float*)d_in[11];
    const float* m3w = (const float*)d_in[12];
    const float* m3b = (const float*)d_in[13];
    const float* m3g = (const float*)d_in[14];
    const float* m3be= (const float*)d_in[15];
    const float* c1w = (const float*)d_in[16];
    const float* c1b = (const float*)d_in[17];
    const float* c1g = (const float*)d_in[18];
    const float* c1be= (const float*)d_in[19];
    const float* c2w = (const float*)d_in[20];
    const float* c2b = (const float*)d_in[21];
    const float* c2g = (const float*)d_in[22];
    const float* c2be= (const float*)d_in[23];
    const float* c3w = (const float*)d_in[24];
    const float* c3b = (const float*)d_in[25];

    char* ws = (char*)d_ws;
    // layout (16B-aligned), total within 53,248,000 B:
    //   [0, 131072)            idx  (2048*16 int32)
    //   [131072, 425984)       W1 padded bf16 (512*288), column-permuted
    //   [425984, 688128)       W2 bf16 (256*512)
    //   [688128, 819200)       W3 bf16 (256*256)
    //   [819200, 19693568)     h0 (32768*288 bf16); dead after gemm1 ->
    //        hp    at +0      (2048*256 bf16 = 1 MB, gemm23 out)
    //        wprep at +1 MB   (3*65536 ushort = 384 KB, gemm23 epilogue out)
    //   [19693568, 53248000)   h1 region (33.55 MB), time-multiplexed:
    //     phase 0 (query):    grid structures at +0 (sorted 640 KB + counts/start/cursor, < 0.75 MB)
    //     phase A (pre-gemm1): featt at +12582912 (2*20000*256 bf16 = 20.48 MB)
    //     phase B: h1 = whole region (gemm1 out, 32768*512 bf16), input to gemm23
    int*            idxs = (int*)ws;
    unsigned short* w1p  = (unsigned short*)(ws + 131072);
    unsigned short* w2p  = (unsigned short*)(ws + 425984);
    unsigned short* w3p  = (unsigned short*)(ws + 688128);
    unsigned short* h0   = (unsigned short*)(ws + 819200);
    unsigned short* hp   = (unsigned short*)(ws + 819200);    // reuses h0 (dead after gemm1)
    unsigned short* wprep= (unsigned short*)(ws + 1867776);   // hp + 1 MB, still in dead-h0 region
    char*           h1b  = ws + 19693568;
    unsigned short* h1   = (unsigned short*)h1b;
    unsigned short* featt= (unsigned short*)(h1b + 12582912);
    float4*         srt  = (float4*)(h1b + 0);            // 40000*16 = 640,000
    int*            gcnt = (int*)(h1b + 640000);          // 8192*4
    int*            gsta = (int*)(h1b + 672768);          // 8193*4 (+pad)
    int*            gcur = (int*)(h1b + 705552);          // 8192*4, ends < 0.75 MB

    hipLaunchKernelGGL(prep_w123z, dim3((O1 * K1P + O2 * 512 + O3 * 256) / 256), dim3(256), 0, stream,
                       m1w, m2w, m3w, w1p, w2p, w3p, gcnt);
    hipLaunchKernelGGL(grid_count, dim3((B_ * N_ + 255) / 256), dim3(256), 0, stream, xyz, gcnt);
    hipLaunchKernelGGL(grid_scan, dim3(1), dim3(256), 0, stream, gcnt, gsta, gcur);
    hipLaunchKernelGGL(grid_scatter, dim3((B_ * N_ + 255) / 256), dim3(256), 0, stream, xyz, gcur, srt);
    hipLaunchKernelGGL(query_transpose, dim3(NQ + TBLK), dim3(256), 0, stream,
                       new_xyz, view_rot, srt, gsta, feat, idxs, featt);
    hipLaunchKernelGGL(build_h0, dim3(NQ), dim3(256), 0, stream, xyz, new_xyz, view_rot, featt, idxs, h0);
    hipLaunchKernelGGL(gemm_bn_relu, dim3(M_ / 128, O1 / 128), dim3(256), 0, stream,
                       h0, w1p, m1b, m1g, m1be, h1, M_, O1, K1P);
    hipLaunchKernelGGL(gemm23_pool, dim3(M_ / 64), dim3(512), 0, stream,
                       h1, w2p, m2b, m2g, m2be, w3p, m3b, m3g, m3be,
                       c1w, c2w, c3w, wprep, hp);
    hipLaunchKernelGGL(head_fused, dim3(NQ / 64), dim3(256), 0, stream,
                       hp, wprep, c1b, c1g, c1be, c2b, c2g, c2be, c3b, (float*)d_out);
}

// Round 15
// 234.618 us; speedup vs baseline: 1.0239x; 1.0239x over previous
//
#include <hip/hip_runtime.h>
#include <hip/hip_bf16.h>
#include <stdint.h>
#include <limits.h>

#define B_   2
#define N_   20000
#define S_   1024
#define C_   256
#define NS_  16
#define NQ   (B_ * S_)        // 2048 queries
#define M_   (NQ * NS_)       // 32768 MLP rows
#define K1P  288              // 259 padded to multiple of 32
#define O1   512
#define O2   256
#define O3   256
#define OUTC 96

#define R2C   ((float)(0.05 * 0.05))
#define HMINC ((float)(-0.02))
#define HMAXC ((float)(0.04))

// spatial grid for cyl query
#define GDIM   16
#define GCELLS (GDIM * GDIM * GDIM)          // 4096 per batch
#define GTOT   (B_ * GCELLS)                 // 8192
#define CAP    256                           // per-wave candidate buffer
#define TBLK   10000                         // transpose blocks fused into query dispatch

__device__ __forceinline__ unsigned short f2b(float f) {
    union { float f; unsigned int i; } x; x.f = f;
    unsigned int r = x.i + 0x7FFFu + ((x.i >> 16) & 1u);   // RNE
    return (unsigned short)(r >> 16);
}

// async global->LDS 16B copy (LDS dest = wave-uniform base + lane*16)
__device__ __forceinline__ void gl16(const unsigned short* g, unsigned short* l) {
    __builtin_amdgcn_global_load_lds(
        (const __attribute__((address_space(1))) unsigned int*)g,
        (__attribute__((address_space(3))) unsigned int*)l,
        16, 0, 0);
}

// ---------------------------------------------------------------- weight prep (fp32 -> bf16) + grid zero
__global__ __launch_bounds__(256) void prep_w123z(const float* __restrict__ m1w,
                                                  const float* __restrict__ m2w,
                                                  const float* __restrict__ m3w,
                                                  unsigned short* __restrict__ w1p,
                                                  unsigned short* __restrict__ w2p,
                                                  unsigned short* __restrict__ w3p,
                                                  int* __restrict__ gcnt) {
    int i = blockIdx.x * 256 + threadIdx.x;
    if (i < GTOT) gcnt[i] = 0;
    if (i < O1 * K1P) {
        int o = i / K1P, k = i - o * K1P;
        float v = 0.0f;
        if (k < 256)      v = m1w[o * 259 + 3 + k];
        else if (k < 259) v = m1w[o * 259 + (k - 256)];
        w1p[i] = (k < 259) ? f2b(v) : (unsigned short)0;
    } else if (i < O1 * K1P + O2 * 512) {
        int j = i - O1 * K1P;
        w2p[j] = f2b(m2w[j]);
    } else if (i < O1 * K1P + O2 * 512 + O3 * 256) {
        int j = i - O1 * K1P - O2 * 512;
        w3p[j] = f2b(m3w[j]);
    }
}

// ---------------------------------------------------------------- grid build: count / scan / scatter
__device__ __forceinline__ int cell_of(float px, float py, float pz, int b) {
    int cx = (int)(px * (float)GDIM); cx = min(GDIM - 1, max(0, cx));
    int cy = (int)(py * (float)GDIM); cy = min(GDIM - 1, max(0, cy));
    int cz = (int)(pz * (float)GDIM); cz = min(GDIM - 1, max(0, cz));
    return b * GCELLS + cz * (GDIM * GDIM) + cy * GDIM + cx;
}

__global__ __launch_bounds__(256) void grid_count(const float* __restrict__ xyz,
                                                  int* __restrict__ counts) {
    int i = blockIdx.x * 256 + threadIdx.x;
    if (i < B_ * N_) {
        int b = i / N_;
        const float* p = xyz + (size_t)i * 3;
        atomicAdd(counts + cell_of(p[0], p[1], p[2], b), 1);
    }
}

// one block, wave-parallel hierarchical scan
__global__ __launch_bounds__(256) void grid_scan(const int* __restrict__ counts,
                                                 int* __restrict__ start,
                                                 int* __restrict__ cursor) {
    __shared__ int wsum[4];
    int t = threadIdx.x, lane = t & 63, wv = t >> 6;
    int local[32];
    int s = 0;
#pragma unroll
    for (int i = 0; i < 32; ++i) { local[i] = counts[t * 32 + i]; s += local[i]; }
    int incl = s;
#pragma unroll
    for (int off = 1; off < 64; off <<= 1) {
        int u = __shfl_up(incl, off);
        if (lane >= off) incl += u;
    }
    if (lane == 63) wsum[wv] = incl;
    __syncthreads();
    int add = 0;
    for (int i = 0; i < wv; ++i) add += wsum[i];
    int r = incl - s + add;                   // exclusive prefix of this thread's 32-chunk
#pragma unroll
    for (int i = 0; i < 32; ++i) {
        start[t * 32 + i] = r;
        cursor[t * 32 + i] = r;
        r += local[i];
    }
    if (t == 255) start[GTOT] = r;
}

__global__ __launch_bounds__(256) void grid_scatter(const float* __restrict__ xyz,
                                                    int* __restrict__ cursor,
                                                    float4* __restrict__ sorted) {
    int i = blockIdx.x * 256 + threadIdx.x;
    if (i < B_ * N_) {
        int b = i / N_, n = i - b * N_;
        const float* p = xyz + (size_t)i * 3;
        float px = p[0], py = p[1], pz = p[2];
        int pos = atomicAdd(cursor + cell_of(px, py, pz, b), 1);
        sorted[pos] = make_float4(px, py, pz, __int_as_float(n));
    }
}

// ---------------------------------------------------------------- wave-parallel select-16-smallest
__device__ __forceinline__ void sort16(int* buf, int cnt, int lane) {
    asm volatile("s_waitcnt lgkmcnt(0)" ::: "memory");
    __builtin_amdgcn_sched_barrier(0);
    int a0 = INT_MAX, a1 = INT_MAX, a2 = INT_MAX, a3 = INT_MAX;
    if (lane < cnt)       a0 = buf[lane];
    if (lane + 64 < cnt)  a1 = buf[lane + 64];
    if (lane + 128 < cnt) a2 = buf[lane + 128];
    if (lane + 192 < cnt) a3 = buf[lane + 192];
#pragma unroll
    for (int t = 0; t < NS_; ++t) {
        int v = a0, sl = 0;
        if (a1 < v) { v = a1; sl = 1; }
        if (a2 < v) { v = a2; sl = 2; }
        if (a3 < v) { v = a3; sl = 3; }
        int pp = (sl << 6) | lane;
#pragma unroll
        for (int off = 1; off < 64; off <<= 1) {
            int ov = __shfl_xor(v, off);
            int op = __shfl_xor(pp, off);
            if (ov < v) { v = ov; pp = op; }
        }
        if ((pp & 63) == lane) {
            int s = pp >> 6;
            if (s == 0) a0 = INT_MAX;
            else if (s == 1) a1 = INT_MAX;
            else if (s == 2) a2 = INT_MAX;
            else a3 = INT_MAX;
        }
        if (lane == 0) buf[t] = v;
    }
    asm volatile("s_waitcnt lgkmcnt(0)" ::: "memory");
    __builtin_amdgcn_sched_barrier(0);
}

// ---------------------------------------------------------------- fused cylinder query + feature transpose
// blockIdx < NQ: one block (4 waves) per query (cell filter + compacted scan).
// blockIdx >= NQ: 32x32 transpose tile of feat [B][C][N] fp32 -> feat_t [B][N][C] bf16.
// Independent outputs; transpose blocks backfill CUs behind query stragglers.
__global__ __launch_bounds__(256) void query_transpose(const float* __restrict__ new_xyz,
                                                       const float* __restrict__ view_rot,
                                                       const float4* __restrict__ sorted,
                                                       const int* __restrict__ cell_start,
                                                       const float* __restrict__ feat,
                                                       int* __restrict__ idx_out,
                                                       unsigned short* __restrict__ feat_t) {
#pragma clang fp contract(off)
    __shared__ int bufs[4][CAP];
    __shared__ int tots[4];
    __shared__ int spnE[4][64];      // exclusive prefix of span lengths (monotone)
    __shared__ int spnS[4][64];      // span starts
    __shared__ float tile[32][33];   // transpose role

    if (blockIdx.x >= NQ) {          // ---------------- transpose role
        int t5 = blockIdx.x - NQ;                 // 0..9999
        int n0 = (t5 % 625) * 32;
        int rem = t5 / 625;                       // 0..15
        int c0 = (rem & 7) * 32;
        int b = rem >> 3;
        int t = threadIdx.x;
        int nl = t & 31;
#pragma unroll
        for (int i = 0; i < 4; ++i) {
            int cl = (t >> 5) + i * 8;
            tile[cl][nl] = feat[((size_t)(b * C_ + c0 + cl)) * N_ + n0 + nl];
        }
        __syncthreads();
        int nr = t >> 3, c4 = (t & 7) * 4;
        ushort4 v;
        v.x = f2b(tile[c4 + 0][nr]);
        v.y = f2b(tile[c4 + 1][nr]);
        v.z = f2b(tile[c4 + 2][nr]);
        v.w = f2b(tile[c4 + 3][nr]);
        *(ushort4*)(feat_t + ((size_t)(b * N_ + n0 + nr)) * C_ + c0 + c4) = v;
        return;
    }

    // ---------------- query role
    int w = threadIdx.x >> 6, lane = threadIdx.x & 63;
    int q = blockIdx.x;
    int b = q >> 10;                 // S_ = 1024
    int* buf = bufs[w];

    const float* nq = new_xyz + (size_t)q * 3;
    float qx = nq[0], qy = nq[1], qz = nq[2];
    const float* rp = view_rot + (size_t)q * 9;
    float R[9];
#pragma unroll
    for (int i = 0; i < 9; ++i) R[i] = rp[i];
    float dq0 = (R[0]*qx + R[1]*qy) + R[2]*qz;
    float dq1 = (R[3]*qx + R[4]*qy) + R[5]*qz;
    float dq2 = (R[6]*qx + R[7]*qy) + R[8]*qz;

    // ---- AABB of {p : hmin < r0 < hmax, r1^2+r2^2 < R^2}, r = V(p-q), via M = V^-1
    int x0 = 0, x1 = GDIM - 1, y0 = 0, y1 = GDIM - 1, z0 = 0, z1 = GDIM - 1;
    {
        float det = R[0]*(R[4]*R[8]-R[5]*R[7])
                  - R[1]*(R[3]*R[8]-R[5]*R[6])
                  + R[2]*(R[3]*R[7]-R[4]*R[6]);
        float adet = fabsf(det);
        if (adet > 1e-30f) {
            float id = 1.0f / det;
            float m00 = (R[4]*R[8]-R[5]*R[7])*id, m01 = (R[2]*R[7]-R[1]*R[8])*id, m02 = (R[1]*R[5]-R[2]*R[4])*id;
            float m10 = (R[5]*R[6]-R[3]*R[8])*id, m11 = (R[0]*R[8]-R[2]*R[6])*id, m12 = (R[2]*R[3]-R[0]*R[5])*id;
            float m20 = (R[3]*R[7]-R[4]*R[6])*id, m21 = (R[1]*R[6]-R[0]*R[7])*id, m22 = (R[0]*R[4]-R[1]*R[3])*id;
            const float mid = 0.5f * (HMINC + HMAXC);   // 0.01
            const float hh  = 0.5f * (HMAXC - HMINC);   // 0.03
            float cx = qx + m00 * mid, cy = qy + m10 * mid, cz = qz + m20 * mid;
            float ex = hh * fabsf(m00) + 0.05f * sqrtf(m01*m01 + m02*m02);
            float ey = hh * fabsf(m10) + 0.05f * sqrtf(m11*m11 + m12*m12);
            float ez = hh * fabsf(m20) + 0.05f * sqrtf(m21*m21 + m22*m22);
            ex = ex * 1.002f + 1e-3f;                   // conservative fp margin
            ey = ey * 1.002f + 1e-3f;
            ez = ez * 1.002f + 1e-3f;
            x0 = (int)fmaxf(0.0f, fminf((float)(GDIM - 1), floorf((cx - ex) * (float)GDIM)));
            x1 = (int)fmaxf(0.0f, fminf((float)(GDIM - 1), floorf((cx + ex) * (float)GDIM)));
            y0 = (int)fmaxf(0.0f, fminf((float)(GDIM - 1), floorf((cy - ey) * (float)GDIM)));
            y1 = (int)fmaxf(0.0f, fminf((float)(GDIM - 1), floorf((cy + ey) * (float)GDIM)));
            z0 = (int)fmaxf(0.0f, fminf((float)(GDIM - 1), floorf((cz - ez) * (float)GDIM)));
            z1 = (int)fmaxf(0.0f, fminf((float)(GDIM - 1), floorf((cz + ez) * (float)GDIM)));
        }
    }

    int ny = y1 - y0 + 1, nz = z1 - z0 + 1;
    int cnt = 0, tot = 0;
    int cbase = b * GCELLS;

    {
        int NR = ny * nz;                         // rows (z,y) in AABB, <= 256
        int nr_w = (NR - w + 3) >> 2;             // rows for this wave (stride 4)
        const float inv16 = 0.0625f, half = 0.03125f;
        float ax = (fabsf(R[0]) + fabsf(R[1]) + fabsf(R[2])) * half + 2e-4f;
        float ay = (fabsf(R[3]) + fabsf(R[4]) + fabsf(R[5])) * half + 2e-4f;
        float az = (fabsf(R[6]) + fabsf(R[7]) + fabsf(R[8])) * half + 2e-4f;
        int sl = 0, el = 0;
        if (lane < nr_w) {                        // one row per lane: tighten x-range
            int ri = w + (lane << 2);
            int zi = ri / ny;
            int yi = ri - zi * ny;
            float cy0 = (y0 + yi + 0.5f) * inv16;
            float cz0 = (z0 + zi + 0.5f) * inv16;
            float cx0 = (x0 + 0.5f) * inv16;
            float xr = (R[0]*cx0 + R[1]*cy0) + R[2]*cz0 - dq0;
            float yr = (R[3]*cx0 + R[4]*cy0) + R[5]*cz0 - dq1;
            float zr = (R[6]*cx0 + R[7]*cy0) + R[8]*cz0 - dq2;
            float sx = R[0] * inv16, sy = R[3] * inv16, sz = R[6] * inv16;
            int xa = 1 << 28, xb = -1;
            for (int cx = x0; cx <= x1; ++cx) {
                bool px = (xr + ax > HMINC) && (xr - ax < HMAXC);
                float dy = fmaxf(fabsf(yr) - ay, 0.0f);
                float dz = fmaxf(fabsf(zr) - az, 0.0f);
                bool pr = (dy*dy + dz*dz) < (R2C + 1e-5f);
                if (px && pr) { if (cx < xa) xa = cx; xb = cx; }
                xr += sx; yr += sy; zr += sz;
            }
            if (xb >= xa) {
                int cid = cbase + (z0 + zi) * (GDIM * GDIM) + (y0 + yi) * GDIM;
                sl = cell_start[cid + xa];
                el = cell_start[cid + xb + 1];
            }
        }

        // ---- work compaction: prefix-sum span lengths across the wave
        int len = el - sl;                        // 0 for inactive/pruned lanes
        int incl = len;
#pragma unroll
        for (int off = 1; off < 64; off <<= 1) {
            int v = __shfl_up(incl, off);
            if (lane >= off) incl += v;
        }
        int T = __shfl(incl, 63);
        spnE[w][lane] = incl - len;
        spnS[w][lane] = sl;
        asm volatile("s_waitcnt lgkmcnt(0)" ::: "memory");
        __builtin_amdgcn_sched_barrier(0);

        for (int g0 = 0; g0 < T; g0 += 64) {
            int g = g0 + lane;
            bool m = false; int n = 0;
            if (g < T) {
                int lo = 0, hi = 63;              // largest j with spnE[j] <= g
#pragma unroll
                for (int it = 0; it < 6; ++it) {
                    int mid = (lo + hi + 1) >> 1;
                    if (spnE[w][mid] <= g) lo = mid; else hi = mid - 1;
                }
                int p = spnS[w][lo] + (g - spnE[w][lo]);
                float4 v = sorted[p];
                n = __float_as_int(v.w);
                float px = v.x, py = v.y, pz = v.z;
                float xr = ((R[0]*px + R[1]*py) + R[2]*pz) - dq0;
                float yr = ((R[3]*px + R[4]*py) + R[5]*pz) - dq1;
                float zr = ((R[6]*px + R[7]*py) + R[8]*pz) - dq2;
                m = ((yr*yr + zr*zr) < R2C) && (xr > HMINC) && (xr < HMAXC);
            }
            unsigned long long bal = __ballot(m);
            if (m) {
                int pos = cnt + __popcll(bal & ((1ull << lane) - 1ull));
                buf[pos] = n;
            }
            int h = __popcll(bal);
            cnt += h; tot += h;
            if (cnt > CAP - 64) { sort16(buf, cnt, lane); cnt = NS_; }
        }
    }

    // per-wave finalize: best 16 ascending in bufs[w][0..15], INT_MAX padded
    sort16(buf, cnt, lane);
    if (lane == 0) tots[w] = tot;
    __syncthreads();

    // merge 4x16 candidates -> global best 16 (wave 0 only)
    if (w == 0) {
        int cand = bufs[lane >> 4][lane & 15];
        int myv = INT_MAX;
#pragma unroll
        for (int t = 0; t < NS_; ++t) {
            int v = cand, pp = lane;
#pragma unroll
            for (int off = 1; off < 64; off <<= 1) {
                int ov = __shfl_xor(v, off);
                int op = __shfl_xor(pp, off);
                if (ov < v) { v = ov; pp = op; }
            }
            if (lane == t) myv = v;               // lane t keeps t-th smallest
            if (pp == lane) cand = INT_MAX;       // owner retires
        }
        int tt = tots[0] + tots[1] + tots[2] + tots[3];
        int total = tt < NS_ ? tt : NS_;
        int first = (tt > 0) ? __shfl(myv, 0) : 0;
        if (lane < NS_)
            idx_out[q * NS_ + lane] = (lane < total) ? myv : first;
    }
}

// ---------------------------------------------------------------- gather + h0
__global__ __launch_bounds__(256) void build_h0(const float* __restrict__ xyz,
                                                const float* __restrict__ new_xyz,
                                                const float* __restrict__ view_rot,
                                                const unsigned short* __restrict__ feat_t,
                                                const int* __restrict__ idxs,
                                                unsigned short* __restrict__ h0) {
#pragma clang fp contract(off)
    int q = blockIdx.x;
    int b = q >> 10;
    int t = threadIdx.x;
    __shared__ int pidx[NS_];
    if (t < NS_) pidx[t] = idxs[q * NS_ + t];
    __syncthreads();

#pragma unroll
    for (int pass = 0; pass < 2; ++pass) {
        int n = pass * 8 + (t >> 5);
        int p = pidx[n];
        uint4 v = *(const uint4*)(feat_t + ((size_t)(b * N_ + p)) * C_ + (t & 31) * 8);
        *(uint4*)(h0 + (size_t)(q * NS_ + n) * K1P + (t & 31) * 8) = v;
    }

    if (t < NS_) {
        int n = t, p = pidx[n];
        const float* pp = xyz + ((size_t)b * N_ + p) * 3;
        const float* nq = new_xyz + (size_t)q * 3;
        float dx = (pp[0] - nq[0]) / 0.05f;
        float dy = (pp[1] - nq[1]) / 0.05f;
        float dz = (pp[2] - nq[2]) / 0.05f;
        const float* rp = view_rot + (size_t)q * 9;
        float r0 = (dx * rp[0] + dy * rp[3]) + dz * rp[6];
        float r1 = (dx * rp[1] + dy * rp[4]) + dz * rp[7];
        float r2 = (dx * rp[2] + dy * rp[5]) + dz * rp[8];
        size_t row = (size_t)(q * NS_ + n) * K1P;
        h0[row + 256] = f2b(r0);
        h0[row + 257] = f2b(r1);
        h0[row + 258] = f2b(r2);
    }
    for (int e = t; e < NS_ * 29; e += 256) {          // zero pad cols 259..287
        int n = e / 29, c = 259 + (e - n * 29);
        h0[(size_t)(q * NS_ + n) * K1P + c] = 0;
    }
}

// ---------------------------------------------------------------- MFMA GEMM + BN + ReLU (gemm1 only)
typedef float f32x4 __attribute__((ext_vector_type(4)));
typedef short s16x8 __attribute__((ext_vector_type(8)));

__global__ __launch_bounds__(256) void gemm_bn_relu(const unsigned short* __restrict__ A,
                                                    const unsigned short* __restrict__ W,
                                                    const float* __restrict__ bias,
                                                    const float* __restrict__ gam,
                                                    const float* __restrict__ bet,
                                                    unsigned short* __restrict__ out,
                                                    int M, int Nn, int K) {
    __shared__ __align__(16) unsigned short As[128 * 32];
    __shared__ __align__(16) unsigned short Bs[128 * 32];
    int tid  = threadIdx.x;
    int lane = tid & 63, wave = tid >> 6;
    int m0 = blockIdx.x * 128, n0 = blockIdx.y * 128;
    int wm = (wave >> 1) * 64, wn = (wave & 1) * 64;

    f32x4 acc[4][4] = {};

    for (int k0 = 0; k0 < K; k0 += 32) {
        __syncthreads();
#pragma unroll
        for (int j = 0; j < 2; ++j) {
            int e = j * 256 + tid;
            int r = e >> 2, c8 = (e & 3) << 3;
            gl16(A + (size_t)(m0 + r) * K + k0 + c8, &As[e * 8]);
            gl16(W + (size_t)(n0 + r) * K + k0 + c8, &Bs[e * 8]);
        }
        __syncthreads();

        int kq = (lane >> 4) * 8, rr = lane & 15;
        s16x8 af[4], bfr[4];
#pragma unroll
        for (int i = 0; i < 4; ++i) af[i]  = *(const s16x8*)&As[(wm + i * 16 + rr) * 32 + kq];
#pragma unroll
        for (int j = 0; j < 4; ++j) bfr[j] = *(const s16x8*)&Bs[(wn + j * 16 + rr) * 32 + kq];
#pragma unroll
        for (int i = 0; i < 4; ++i)
#pragma unroll
            for (int j = 0; j < 4; ++j)
                acc[i][j] = __builtin_amdgcn_mfma_f32_16x16x32_bf16(af[i], bfr[j], acc[i][j], 0, 0, 0);
    }

    float inv = 1.0f / sqrtf(1.0f + 1e-5f);
    int col = lane & 15, rq = (lane >> 4) * 4;
#pragma unroll
    for (int j = 0; j < 4; ++j) {
        int n = n0 + wn + j * 16 + col;
        float sc = gam[n] * inv;
        float tb = bias[n] * sc + bet[n];
#pragma unroll
        for (int i = 0; i < 4; ++i) {
            int mbase = m0 + wm + i * 16 + rq;
#pragma unroll
            for (int r = 0; r < 4; ++r) {
                float v = acc[i][j][r] * sc + tb;
                v = fmaxf(v, 0.0f);
                out[(size_t)(mbase + r) * Nn + n] = f2b(v);
            }
        }
    }
}

// ---------------------------------------------------------------- fused gemm2 + gemm3 + maxpool (+ head-weight prep)
// 64-row blocks (4 queries), 512 threads (8 waves: 4 m-strips x 2 n-halves), LDS 52 KB.
// Block->tile map XCD-MATCHED to gemm1's h1 writer: gemm1 stripe i (rows 128i) runs
// entirely on XCD i%8 (grid (256,4), x-fastest => linear%8 == x%8); we map reader
// block bid=8g+xcd to tile mt with (mt>>1)%8 == xcd, so h1 reads hit the L2 that
// holds the freshly written lines. Bijective over [0,512). Perf heuristic only.
__global__ __launch_bounds__(512) void gemm23_pool(const unsigned short* __restrict__ A,   // h1 [M][512]
                                                   const unsigned short* __restrict__ W2,  // [256][512]
                                                   const float* __restrict__ bias2,
                                                   const float* __restrict__ gam2,
                                                   const float* __restrict__ bet2,
                                                   const unsigned short* __restrict__ W3,  // [256][256]
                                                   const float* __restrict__ bias3,
                                                   const float* __restrict__ gam3,
                                                   const float* __restrict__ bet3,
                                                   const float* __restrict__ c1w,
                                                   const float* __restrict__ c2w,
                                                   const float* __restrict__ c3w,
                                                   unsigned short* __restrict__ wprep,
                                                   unsigned short* __restrict__ hp) {      // [2048][256]
    __shared__ __align__(16) unsigned short As[64 * 32];     // 4 KB
    __shared__ __align__(16) unsigned short Bs[256 * 32];    // 16 KB
    __shared__ __align__(16) unsigned short H2[64 * 256];    // 32 KB, swizzled
    int tid = threadIdx.x, lane = tid & 63, wave = tid >> 6;
    int bid = blockIdx.x;
    int xcd = bid & 7, gg = bid >> 3;
    int mt = 16 * (gg >> 1) + 2 * xcd + (gg & 1);            // (mt>>1)%8 == xcd
    int m0 = mt * 64;
    int wm = (wave >> 1) * 16, wn = (wave & 1) * 128;
    int kq = (lane >> 4) * 8, rr = lane & 15;
    int col = lane & 15, rq = (lane >> 4) * 4;
    float inv = 1.0f / sqrtf(1.0f + 1e-5f);

    f32x4 acc[8] = {};

    // -------- phase 1: K=512
    for (int k0 = 0; k0 < 512; k0 += 32) {
        __syncthreads();
        if (tid < 256) {
            int r = tid >> 2, c8 = (tid & 3) << 3;
            gl16(A + (size_t)(m0 + r) * 512 + k0 + c8, &As[tid * 8]);
        }
#pragma unroll
        for (int j = 0; j < 2; ++j) {
            int e = j * 512 + tid;
            int r = e >> 2, c8 = (e & 3) << 3;
            gl16(W2 + (size_t)r * 512 + k0 + c8, &Bs[e * 8]);
        }
        __syncthreads();
        s16x8 af = *(const s16x8*)&As[(wm + rr) * 32 + kq];
        s16x8 bf[8];
#pragma unroll
        for (int j = 0; j < 8; ++j) bf[j] = *(const s16x8*)&Bs[(wn + j * 16 + rr) * 32 + kq];
#pragma unroll
        for (int j = 0; j < 8; ++j)
            acc[j] = __builtin_amdgcn_mfma_f32_16x16x32_bf16(af, bf[j], acc[j], 0, 0, 0);
    }

    // head-weight prep: 384 elements per block, disjoint (uses RAW bid; still a bijection)
    {
        int e = bid * 384 + tid;
        if (tid < 384) {
            int l = e >> 16, j = e & 65535, row = j >> 8, kcol = j & 255;
            float v;
            if (l == 0)      v = c1w[j];
            else if (l == 1) v = c2w[j];
            else             v = (row < OUTC) ? c3w[row * 256 + kcol] : 0.0f;
            int c = kcol & 127;
            wprep[l * 65536 + (kcol >> 7) * 32768 + row * 128 + (c ^ ((row & 7) << 3))] = f2b(v);
        }
    }

    // epilogue1: bn2+relu -> H2 (swizzled: byte ^= (row&7)<<4)
#pragma unroll
    for (int j = 0; j < 8; ++j) {
        int n = wn + j * 16 + col;
        float sc = gam2[n] * inv;
        float tb = bias2[n] * sc + bet2[n];
#pragma unroll
        for (int r = 0; r < 4; ++r) {
            int row = wm + rq + r;
            float v = fmaxf(acc[j][r] * sc + tb, 0.0f);
            *(unsigned short*)((char*)H2 + row * 512 + ((2 * n) ^ ((row & 7) << 4))) = f2b(v);
        }
    }

    // -------- phase 2: K=256 from H2(LDS), W3 streamed
#pragma unroll
    for (int j = 0; j < 8; ++j) acc[j] = (f32x4){0.f, 0.f, 0.f, 0.f};

    for (int k0 = 0; k0 < 256; k0 += 32) {
        __syncthreads();
#pragma unroll
        for (int j = 0; j < 2; ++j) {
            int e = j * 512 + tid;
            int r = e >> 2, c8 = (e & 3) << 3;
            gl16(W3 + (size_t)r * 256 + k0 + c8, &Bs[e * 8]);
        }
        __syncthreads();
        int row = wm + rr;
        s16x8 af = *(const s16x8*)((const char*)H2 + row * 512 + ((2 * (k0 + kq)) ^ ((row & 7) << 4)));
        s16x8 bf[8];
#pragma unroll
        for (int j = 0; j < 8; ++j) bf[j] = *(const s16x8*)&Bs[(wn + j * 16 + rr) * 32 + kq];
#pragma unroll
        for (int j = 0; j < 8; ++j)
            acc[j] = __builtin_amdgcn_mfma_f32_16x16x32_bf16(af, bf[j], acc[j], 0, 0, 0);
    }

    // epilogue2: bn3+relu + 16-row maxpool (each wave's 16 rows = 1 query)
    int qbase = (m0 + wm) >> 4;
#pragma unroll
    for (int j = 0; j < 8; ++j) {
        int n = wn + j * 16 + col;
        float sc = gam3[n] * inv;
        float tb = bias3[n] * sc + bet3[n];
        float mx = 0.0f;                          // relu floor
#pragma unroll
        for (int r = 0; r < 4; ++r)
            mx = fmaxf(mx, acc[j][r] * sc + tb);
        mx = fmaxf(mx, __shfl_xor(mx, 16, 64));
        mx = fmaxf(mx, __shfl_xor(mx, 32, 64));
        if (lane < 16)
            hp[(size_t)qbase * 256 + n] = f2b(mx);
    }
}

// ---------------------------------------------------------------- fused head: hp -> c1 -> c2 -> c3 -> out
__device__ __forceinline__ void head_gemm(const unsigned short* __restrict__ act,
                                          unsigned short* __restrict__ Ws,
                                          const unsigned short* __restrict__ Wp,  // layer base in wprep
                                          int tid, int lane, int wn, f32x4 acc[4][4]) {
    int kq = (lane >> 4) * 8, rr = lane & 15;
    for (int h = 0; h < 2; ++h) {
        __syncthreads();                          // Ws free (previous mma done)
        const unsigned short* src = Wp + h * 32768;
#pragma unroll
        for (int p = 0; p < 16; ++p)
            gl16(src + (p * 256 + tid) * 8, Ws + (p * 256 + tid) * 8);
        __syncthreads();                          // drains vmcnt -> Ws ready
        int k0 = h * 128;
#pragma unroll
        for (int kk = 0; kk < 128; kk += 32) {
            s16x8 af[4], bf[4];
#pragma unroll
            for (int i = 0; i < 4; ++i) {
                int row = i * 16 + rr;
                af[i] = *(const s16x8*)((const char*)act + row * 512 + ((2 * (k0 + kk + kq)) ^ ((row & 7) << 4)));
            }
#pragma unroll
            for (int j = 0; j < 4; ++j) {
                int row = wn + j * 16 + rr;
                bf[j] = *(const s16x8*)&Ws[row * 128 + ((kk + kq) ^ ((row & 7) << 3))];
            }
#pragma unroll
            for (int i = 0; i < 4; ++i)
#pragma unroll
                for (int j = 0; j < 4; ++j)
                    acc[i][j] = __builtin_amdgcn_mfma_f32_16x16x32_bf16(af[i], bf[j], acc[i][j], 0, 0, 0);
        }
    }
}

__global__ __launch_bounds__(256) void head_fused(const unsigned short* __restrict__ hp,
                                                  const unsigned short* __restrict__ wp,
                                                  const float* __restrict__ c1b,
                                                  const float* __restrict__ c1g, const float* __restrict__ c1be,
                                                  const float* __restrict__ c2b,
                                                  const float* __restrict__ c2g, const float* __restrict__ c2be,
                                                  const float* __restrict__ c3b,
                                                  float* __restrict__ out) {
    __shared__ __align__(16) unsigned short actA[64 * 256];   // 32 KB, swizzled
    __shared__ __align__(16) unsigned short actB[64 * 256];   // 32 KB, swizzled
    __shared__ __align__(16) unsigned short Ws[256 * 128];    // 64 KB, pre-swizzled halves
    int tid = threadIdx.x, lane = tid & 63, wave = tid >> 6;
    int q0 = blockIdx.x * 64;
    int wn = wave * 64, col = lane & 15, rq = (lane >> 4) * 4;
    float inv = 1.0f / sqrtf(1.0f + 1e-5f);

    // stage hp rows -> actA (swizzled)
#pragma unroll
    for (int j = 0; j < 8; ++j) {
        int c = j * 256 + tid;
        int row = c >> 5, cb = c & 31;
        uint4 v = *(const uint4*)(hp + (size_t)(q0 + row) * 256 + cb * 8);
        *(uint4*)((char*)actA + row * 512 + (((unsigned)cb << 4) ^ ((row & 7) << 4))) = v;
    }

    f32x4 acc[4][4];

    // ---- layer c1: actA -> actB
#pragma unroll
    for (int i = 0; i < 4; ++i)
#pragma unroll
        for (int j = 0; j < 4; ++j) acc[i][j] = (f32x4){0.f, 0.f, 0.f, 0.f};
    head_gemm(actA, Ws, wp, tid, lane, wn, acc);
#pragma unroll
    for (int j = 0; j < 4; ++j) {
        int n = wn + j * 16 + col;
        float sc = c1g[n] * inv, tb = c1b[n] * sc + c1be[n];
#pragma unroll
        for (int i = 0; i < 4; ++i)
#pragma unroll
            for (int r = 0; r < 4; ++r) {
                int row = i * 16 + rq + r;
                float v = fmaxf(acc[i][j][r] * sc + tb, 0.0f);
                *(unsigned short*)((char*)actB + row * 512 + ((2 * n) ^ ((row & 7) << 4))) = f2b(v);
            }
    }

    // ---- layer c2: actB -> actA
#pragma unroll
    for (int i = 0; i < 4; ++i)
#pragma unroll
        for (int j = 0; j < 4; ++j) acc[i][j] = (f32x4){0.f, 0.f, 0.f, 0.f};
    head_gemm(actB, Ws, wp + 65536, tid, lane, wn, acc);
#pragma unroll
    for (int j = 0; j < 4; ++j) {
        int n = wn + j * 16 + col;
        float sc = c2g[n] * inv, tb = c2b[n] * sc + c2be[n];
#pragma unroll
        for (int i = 0; i < 4; ++i)
#pragma unroll
            for (int r = 0; r < 4; ++r) {
                int row = i * 16 + rq + r;
                float v = fmaxf(acc[i][j][r] * sc + tb, 0.0f);
                *(unsigned short*)((char*)actA + row * 512 + ((2 * n) ^ ((row & 7) << 4))) = f2b(v);
            }
    }

    // ---- layer c3: actA -> out (fp32, N=96, no bn/relu)
#pragma unroll
    for (int i = 0; i < 4; ++i)
#pragma unroll
        for (int j = 0; j < 4; ++j) acc[i][j] = (f32x4){0.f, 0.f, 0.f, 0.f};
    head_gemm(actA, Ws, wp + 131072, tid, lane, wn, acc);
#pragma unroll
    for (int j = 0; j < 4; ++j) {
        int n = wn + j * 16 + col;
        if (n < OUTC) {
            float bb = c3b[n];
#pragma unroll
            for (int i = 0; i < 4; ++i)
#pragma unroll
                for (int r = 0; r < 4; ++r)
                    out[(size_t)(q0 + i * 16 + rq + r) * OUTC + n] = acc[i][j][r] + bb;
        }
    }
}

// ---------------------------------------------------------------- launch
extern "C" void kernel_launch(void* const* d_in, const int* in_sizes, int n_in,
                              void* d_out, int out_size, void* d_ws, size_t ws_size,
                              hipStream_t stream) {
    const float* xyz      = (const float*)d_in[0];
    const float* new_xyz  = (const float*)d_in[1];
    const float* view_rot = (const float*)d_in[2];
    const float* feat     = (const float*)d_in[3];
    const float* m1w = (const float*)d_in[4];
    const float* m1b = (const float*)d_in[5];
    const float* m1g = (const float*)d_in[6];
    const float* m1be= (const float*)d_in[7];
    const float* m2w = (const float*)d_in[8];
    const float* m2b = (const float*)d_in[9];
    const float* m2g = (const float*)d_in[10];
    const float* m2be= (const float*)d_in[11];
    const float* m3w = (const float*)d_in[12];
    const float* m3b = (const float*)d_in[13];
    const float* m3g = (const float*)d_in[14];
    const float* m3be= (const float*)d_in[15];
    const float* c1w = (const float*)d_in[16];
    const float* c1b = (const float*)d_in[17];
    const float* c1g = (const float*)d_in[18];
    const float* c1be= (const float*)d_in[19];
    const float* c2w = (const float*)d_in[20];
    const float* c2b = (const float*)d_in[21];
    const float* c2g = (const float*)d_in[22];
    const float* c2be= (const float*)d_in[23];
    const float* c3w = (const float*)d_in[24];
    const float* c3b = (const float*)d_in[25];

    char* ws = (char*)d_ws;
    // layout (16B-aligned), total within 53,248,000 B:
    //   [0, 131072)            idx  (2048*16 int32)
    //   [131072, 425984)       W1 padded bf16 (512*288), column-permuted
    //   [425984, 688128)       W2 bf16 (256*512)
    //   [688128, 819200)       W3 bf16 (256*256)
    //   [819200, 19693568)     h0 (32768*288 bf16); dead after gemm1 ->
    //        hp    at +0      (2048*256 bf16 = 1 MB, gemm23 out)
    //        wprep at +1 MB   (3*65536 ushort = 384 KB, gemm23 epilogue out)
    //   [19693568, 53248000)   h1 region (33.55 MB), time-multiplexed:
    //     phase 0 (query):    grid structures at +0 (sorted 640 KB + counts/start/cursor, < 0.75 MB)
    //     phase A (pre-gemm1): featt at +12582912 (2*20000*256 bf16 = 20.48 MB)
    //     phase B: h1 = whole region (gemm1 out, 32768*512 bf16), input to gemm23
    int*            idxs = (int*)ws;
    unsigned short* w1p  = (unsigned short*)(ws + 131072);
    unsigned short* w2p  = (unsigned short*)(ws + 425984);
    unsigned short* w3p  = (unsigned short*)(ws + 688128);
    unsigned short* h0   = (unsigned short*)(ws + 819200);
    unsigned short* hp   = (unsigned short*)(ws + 819200);    // reuses h0 (dead after gemm1)
    unsigned short* wprep= (unsigned short*)(ws + 1867776);   // hp + 1 MB, still in dead-h0 region
    char*           h1b  = ws + 19693568;
    unsigned short* h1   = (unsigned short*)h1b;
    unsigned short* featt= (unsigned short*)(h1b + 12582912);
    float4*         srt  = (float4*)(h1b + 0);            // 40000*16 = 640,000
    int*            gcnt = (int*)(h1b + 640000);          // 8192*4
    int*            gsta = (int*)(h1b + 672768);          // 8193*4 (+pad)
    int*            gcur = (int*)(h1b + 705552);          // 8192*4, ends < 0.75 MB

    hipLaunchKernelGGL(prep_w123z, dim3((O1 * K1P + O2 * 512 + O3 * 256) / 256), dim3(256), 0, stream,
                       m1w, m2w, m3w, w1p, w2p, w3p, gcnt);
    hipLaunchKernelGGL(grid_count, dim3((B_ * N_ + 255) / 256), dim3(256), 0, stream, xyz, gcnt);
    hipLaunchKernelGGL(grid_scan, dim3(1), dim3(256), 0, stream, gcnt, gsta, gcur);
    hipLaunchKernelGGL(grid_scatter, dim3((B_ * N_ + 255) / 256), dim3(256), 0, stream, xyz, gcur, srt);
    hipLaunchKernelGGL(query_transpose, dim3(NQ + TBLK), dim3(256), 0, stream,
                       new_xyz, view_rot, srt, gsta, feat, idxs, featt);
    hipLaunchKernelGGL(build_h0, dim3(NQ), dim3(256), 0, stream, xyz, new_xyz, view_rot, featt, idxs, h0);
    hipLaunchKernelGGL(gemm_bn_relu, dim3(M_ / 128, O1 / 128), dim3(256), 0, stream,
                       h0, w1p, m1b, m1g, m1be, h1, M_, O1, K1P);
    hipLaunchKernelGGL(gemm23_pool, dim3(M_ / 64), dim3(512), 0, stream,
                       h1, w2p, m2b, m2g, m2be, w3p, m3b, m3g, m3be,
                       c1w, c2w, c3w, wprep, hp);
    hipLaunchKernelGGL(head_fused, dim3(NQ / 64), dim3(256), 0, stream,
                       hp, wprep, c1b, c1g, c1be, c2b, c2g, c2be, c3b, (float*)d_out);
}